// Round 1
// baseline (1710.670 us; speedup 1.0000x reference)
//
#include <hip/hip_runtime.h>

#define NUM_USERS 100000
#define NUM_ITEMS 50000
#define NUM_EDGES 4000000
#define DIM 64

// One 64-lane wave per edge; lane d owns dimension d.
// Gather user/item rows (coalesced 256B per wave), scale by norm,
// scatter with device-scope atomicAdd (coalesced 256B per wave).
__global__ __launch_bounds__(256) void lightgcn_scatter(
    const float* __restrict__ user_emb,
    const float* __restrict__ item_emb,
    const float* __restrict__ edge_norm,
    const int* __restrict__ u_idx,
    const int* __restrict__ i_idx,
    float* __restrict__ agg_users,
    float* __restrict__ agg_items)
{
    long long gid = (long long)blockIdx.x * blockDim.x + threadIdx.x;
    int edge = (int)(gid >> 6);
    int lane = (int)(gid & 63);
    if (edge >= NUM_EDGES) return;

    int u = u_idx[edge];
    int i = i_idx[edge];
    float n = edge_norm[edge];

    float uval = user_emb[(size_t)u * DIM + lane];
    float ival = item_emb[(size_t)i * DIM + lane];

    atomicAdd(&agg_items[(size_t)i * DIM + lane], n * uval);
    atomicAdd(&agg_users[(size_t)u * DIM + lane], n * ival);
}

extern "C" void kernel_launch(void* const* d_in, const int* in_sizes, int n_in,
                              void* d_out, int out_size, void* d_ws, size_t ws_size,
                              hipStream_t stream) {
    const float* user_emb  = (const float*)d_in[0];
    const float* item_emb  = (const float*)d_in[1];
    const float* edge_norm = (const float*)d_in[2];
    const int*   u_idx     = (const int*)d_in[3];
    const int*   i_idx     = (const int*)d_in[4];

    float* agg_users = (float*)d_out;                          // 100000*64
    float* agg_items = agg_users + (size_t)NUM_USERS * DIM;    // 50000*64

    // d_out is re-poisoned to 0xAA before every timed call — zero it here.
    hipMemsetAsync(d_out, 0, (size_t)out_size * sizeof(float), stream);

    const int threads = 256;
    const long long total_threads = (long long)NUM_EDGES * 64;
    const int blocks = (int)((total_threads + threads - 1) / threads);

    lightgcn_scatter<<<blocks, threads, 0, stream>>>(
        user_emb, item_emb, edge_norm, u_idx, i_idx, agg_users, agg_items);
}

// Round 2
// 1368.773 us; speedup vs baseline: 1.2498x; 1.2498x over previous
//
#include <hip/hip_runtime.h>

#define NUM_USERS 100000
#define NUM_ITEMS 50000
#define NUM_EDGES 4000000
#define DIM 64

// ---------------- fallback: scatter-atomic (round-1 kernel) ----------------
__global__ __launch_bounds__(256) void lightgcn_scatter(
    const float* __restrict__ user_emb,
    const float* __restrict__ item_emb,
    const float* __restrict__ edge_norm,
    const int* __restrict__ u_idx,
    const int* __restrict__ i_idx,
    float* __restrict__ agg_users,
    float* __restrict__ agg_items)
{
    long long gid = (long long)blockIdx.x * blockDim.x + threadIdx.x;
    int edge = (int)(gid >> 6);
    int lane = (int)(gid & 63);
    if (edge >= NUM_EDGES) return;
    int u = u_idx[edge];
    int i = i_idx[edge];
    float n = edge_norm[edge];
    float uval = user_emb[(size_t)u * DIM + lane];
    float ival = item_emb[(size_t)i * DIM + lane];
    atomicAdd(&agg_items[(size_t)i * DIM + lane], n * uval);
    atomicAdd(&agg_users[(size_t)u * DIM + lane], n * ival);
}

// ---------------- CSR build ----------------
__global__ __launch_bounds__(256) void edge_hist(
    const int* __restrict__ u_idx, const int* __restrict__ i_idx,
    int* __restrict__ u_cnt, int* __restrict__ i_cnt)
{
    int e = blockIdx.x * blockDim.x + threadIdx.x;
    if (e >= NUM_EDGES) return;
    atomicAdd(&i_cnt[i_idx[e]], 1);
    atomicAdd(&u_cnt[u_idx[e]], 1);
}

// grid=2: block 0 scans item counts (n=NUM_ITEMS), block 1 scans user counts.
// In-place: cnt[] becomes exclusive offsets, cnt[n] = total, cur[] = offsets copy.
__global__ __launch_bounds__(1024) void scan_offsets(
    int* __restrict__ i_off, int* __restrict__ i_cur,
    int* __restrict__ u_off, int* __restrict__ u_cur)
{
    int* cnt; int* cur; int n;
    if (blockIdx.x == 0) { cnt = i_off; cur = i_cur; n = NUM_ITEMS; }
    else                 { cnt = u_off; cur = u_cur; n = NUM_USERS; }
    const int t = threadIdx.x;
    const int chunk = (n + 1023) / 1024;
    const int base = t * chunk;
    const int lim  = (base + chunk < n) ? base + chunk : n;

    int local = 0;
    for (int i = base; i < lim; ++i) local += cnt[i];

    __shared__ int s[1024];
    s[t] = local;
    __syncthreads();
    for (int off = 1; off < 1024; off <<= 1) {
        int v = (t >= off) ? s[t - off] : 0;
        __syncthreads();
        s[t] += v;
        __syncthreads();
    }
    int running = (t == 0) ? 0 : s[t - 1];
    if (t == 1023) cnt[n] = s[1023];   // total; slot n untouched by chunks
    for (int i = base; i < lim; ++i) {
        int c = cnt[i];
        cnt[i] = running;   // in-place count -> exclusive offset (own chunk only)
        cur[i] = running;   // placement cursor
        running += c;
    }
}

__global__ __launch_bounds__(256) void edge_place(
    const int* __restrict__ u_idx, const int* __restrict__ i_idx,
    const float* __restrict__ edge_norm,
    int* __restrict__ i_cur, int* __restrict__ u_cur,
    int* __restrict__ ci_src, float* __restrict__ ci_w,
    int* __restrict__ cu_src, float* __restrict__ cu_w)
{
    int e = blockIdx.x * blockDim.x + threadIdx.x;
    if (e >= NUM_EDGES) return;
    int u = u_idx[e];
    int i = i_idx[e];
    float w = edge_norm[e];
    int pi = atomicAdd(&i_cur[i], 1);
    ci_src[pi] = u;  ci_w[pi] = w;
    int pu = atomicAdd(&u_cur[u], 1);
    cu_src[pu] = i;  cu_w[pu] = w;
}

// ---------------- gather: one 64-lane wave per output row ----------------
__global__ __launch_bounds__(256) void gather_rows(
    const int* __restrict__ off, const int* __restrict__ src,
    const float* __restrict__ w, const float* __restrict__ emb,
    float* __restrict__ out, int nrows)
{
    int gid  = blockIdx.x * blockDim.x + threadIdx.x;
    int row  = gid >> 6;
    int lane = gid & 63;
    if (row >= nrows) return;
    int s = off[row];
    int e = off[row + 1];
    float acc = 0.f;
    int k = s;
    for (; k + 4 <= e; k += 4) {
        int   u0 = src[k],   u1 = src[k+1], u2 = src[k+2], u3 = src[k+3];
        float w0 = w[k],     w1 = w[k+1],   w2 = w[k+2],   w3 = w[k+3];
        float v0 = emb[(size_t)u0 * DIM + lane];
        float v1 = emb[(size_t)u1 * DIM + lane];
        float v2 = emb[(size_t)u2 * DIM + lane];
        float v3 = emb[(size_t)u3 * DIM + lane];
        acc += w0 * v0;
        acc += w1 * v1;
        acc += w2 * v2;
        acc += w3 * v3;
    }
    for (; k < e; ++k) acc += w[k] * emb[(size_t)src[k] * DIM + lane];
    out[(size_t)row * DIM + lane] = acc;
}

extern "C" void kernel_launch(void* const* d_in, const int* in_sizes, int n_in,
                              void* d_out, int out_size, void* d_ws, size_t ws_size,
                              hipStream_t stream) {
    const float* user_emb  = (const float*)d_in[0];
    const float* item_emb  = (const float*)d_in[1];
    const float* edge_norm = (const float*)d_in[2];
    const int*   u_idx     = (const int*)d_in[3];
    const int*   i_idx     = (const int*)d_in[4];

    float* agg_users = (float*)d_out;                        // 100000*64
    float* agg_items = agg_users + (size_t)NUM_USERS * DIM;  // 50000*64

    // Workspace layout
    const size_t need = ((size_t)(NUM_ITEMS + 1) + (NUM_USERS + 1)
                       + NUM_ITEMS + NUM_USERS) * sizeof(int)
                      + (size_t)NUM_EDGES * 2 * (sizeof(int) + sizeof(float));

    if (ws_size < need) {
        // fallback: scatter-atomic path
        hipMemsetAsync(d_out, 0, (size_t)out_size * sizeof(float), stream);
        const long long total_threads = (long long)NUM_EDGES * 64;
        const int blocks = (int)((total_threads + 255) / 256);
        lightgcn_scatter<<<blocks, 256, 0, stream>>>(
            user_emb, item_emb, edge_norm, u_idx, i_idx, agg_users, agg_items);
        return;
    }

    char* p = (char*)d_ws;
    int*   i_off   = (int*)p;   p += (size_t)(NUM_ITEMS + 1) * sizeof(int);
    int*   u_off   = (int*)p;   p += (size_t)(NUM_USERS + 1) * sizeof(int);
    int*   i_cur   = (int*)p;   p += (size_t)NUM_ITEMS * sizeof(int);
    int*   u_cur   = (int*)p;   p += (size_t)NUM_USERS * sizeof(int);
    int*   ci_src  = (int*)p;   p += (size_t)NUM_EDGES * sizeof(int);
    float* ci_w    = (float*)p; p += (size_t)NUM_EDGES * sizeof(float);
    int*   cu_src  = (int*)p;   p += (size_t)NUM_EDGES * sizeof(int);
    float* cu_w    = (float*)p; p += (size_t)NUM_EDGES * sizeof(float);

    // zero count arrays (i_off and u_off are contiguous)
    hipMemsetAsync(i_off, 0, (size_t)(NUM_ITEMS + 1 + NUM_USERS + 1) * sizeof(int),
                   stream);

    const int eblocks = (NUM_EDGES + 255) / 256;
    edge_hist<<<eblocks, 256, 0, stream>>>(u_idx, i_idx, u_off, i_off);
    scan_offsets<<<2, 1024, 0, stream>>>(i_off, i_cur, u_off, u_cur);
    edge_place<<<eblocks, 256, 0, stream>>>(u_idx, i_idx, edge_norm,
                                            i_cur, u_cur, ci_src, ci_w, cu_src, cu_w);

    // agg_items[i] = sum over edges with i_idx==i of norm * user_emb[u]
    {
        const int blocks = ((NUM_ITEMS * 64) + 255) / 256;
        gather_rows<<<blocks, 256, 0, stream>>>(i_off, ci_src, ci_w, user_emb,
                                                agg_items, NUM_ITEMS);
    }
    // agg_users[u] = sum over edges with u_idx==u of norm * item_emb[i]
    {
        const int blocks = ((NUM_USERS * 64) + 255) / 256;
        gather_rows<<<blocks, 256, 0, stream>>>(u_off, cu_src, cu_w, item_emb,
                                                agg_users, NUM_USERS);
    }
}